// Round 14
// baseline (145.377 us; speedup 1.0000x reference)
//
#include <hip/hip_runtime.h>
#include <hip/hip_bf16.h>

// CrossNATBlock2D: B=1, H=W=128, C=128, HEADS=4, HD=32, K=7  (fp32 I/O)
// R31: delete R30's phase-0b (per-block staging of the FULL 1.25MB qv/k
// weight set into LDS was on the critical path — it ate the launch-merge
// win). k_qkv B-frags now convert fp32->bf16 at load via PLAIN C
// __float2bfloat16 (RNE, same numerics; NOT R28's inline-asm pattern),
// one load per fragment reused x4 m-tiles. This also bisects R28's NaN:
// only {C-conversion x k_qkv} changes; k_fam byte-identical to R13's
// passing 43.6us body (reads phase-0a pre-converted ws). LDS 139->34.8KB.

#define N_PIX 16384
#define C 128
#define HEADS 4
#define HD 32
#define HW 128

typedef __hip_bfloat16 bf16;
typedef __attribute__((ext_vector_type(8))) short bf16x8;
typedef __attribute__((ext_vector_type(4))) float f32x4;

__device__ __forceinline__ short f2bs(float f) {
    unsigned int r;
    asm("v_cvt_pk_bf16_f32 %0, %1, %2" : "=v"(r) : "v"(f), "v"(f));
    return (short)(r & 0xffff);
}
__device__ __forceinline__ unsigned int pack2(float a, float b) {
    unsigned int r;
    asm("v_cvt_pk_bf16_f32 %0, %1, %2" : "=v"(r) : "v"(a), "v"(b));
    return r;
}
__device__ __forceinline__ float bs2f(short s) {
    __hip_bfloat16_raw r; r.x = (unsigned short)s;
    return __bfloat162float(__hip_bfloat16(r));
}
__device__ __forceinline__ float gelu_f(float v) {
    const float z2 = v * (2.302236206f + 0.102943322f * v * v);
    return v / (1.f + exp2f(-z2));
}
// plain-C fp32x8 -> bf16x8 fragment load (RNE via __float2bfloat16; no asm)
__device__ __forceinline__ bf16x8 ldw8c(const float* __restrict__ p) {
    const float4 a = *(const float4*)p;
    const float4 b = *(const float4*)(p + 4);
    bf16x8 v;
    v[0] = (short)__bfloat16_as_ushort(__float2bfloat16(a.x));
    v[1] = (short)__bfloat16_as_ushort(__float2bfloat16(a.y));
    v[2] = (short)__bfloat16_as_ushort(__float2bfloat16(a.z));
    v[3] = (short)__bfloat16_as_ushort(__float2bfloat16(a.w));
    v[4] = (short)__bfloat16_as_ushort(__float2bfloat16(b.x));
    v[5] = (short)__bfloat16_as_ushort(__float2bfloat16(b.y));
    v[6] = (short)__bfloat16_as_ushort(__float2bfloat16(b.z));
    v[7] = (short)__bfloat16_as_ushort(__float2bfloat16(b.w));
    return v;
}

// ---------- kernel 1: wconv prologue + LN1 + QV GEMM + K proj ----------
// 64 px/block, 512 thr, grid 256. B-frags converted at load (C path).
__global__ __launch_bounds__(512, 4) void k_qkv(
    const float* __restrict__ x, const float* __restrict__ y,
    const float* __restrict__ qv_w, const float* __restrict__ qv_b,
    const float* __restrict__ k_w, const float* __restrict__ k_b,
    const float* __restrict__ n1_w, const float* __restrict__ n1_b,
    const float* __restrict__ proj_w, const float* __restrict__ fc1_w,
    const float* __restrict__ fc2_w,
    bf16* __restrict__ qb, bf16* __restrict__ vb, bf16* __restrict__ kb,
    short* __restrict__ wproj, short* __restrict__ wfc1,
    short* __restrict__ wfc2) {
    __shared__ short xn[64][136];         //  17,408 B
    __shared__ short yl[64][136];         //  17,408 B  (total 34,816 B)
    const int t = threadIdx.x;
    const int pix0 = ((blockIdx.x & 7) * 32 + (blockIdx.x >> 3)) * 64;
    // ---- phase 0a: convert proj/fc1/fc2 -> ws (k_fam consumers only;
    //      disjoint global writes, stream-ordered across kernel boundary) ----
    {
        const int gi = blockIdx.x * 512 + t;          // 0..131071
        if (gi < 16384) wproj[gi] = f2bs(proj_w[gi]);
        if (gi < 65536) { wfc1[gi] = f2bs(fc1_w[gi]); wfc2[gi] = f2bs(fc2_w[gi]); }
    }
    // ---- phase 0b: fused stage + LN1 (thread owns row = t>>3, c16) ----
    {
        const int r = t >> 3, c16 = (t & 7) * 16;
        const size_t gp = (size_t)(pix0 + r) * C + c16;
        float xv[16], yv[16];
        *(float4*)&xv[0]  = *(const float4*)(x + gp);
        *(float4*)&xv[4]  = *(const float4*)(x + gp + 4);
        *(float4*)&xv[8]  = *(const float4*)(x + gp + 8);
        *(float4*)&xv[12] = *(const float4*)(x + gp + 12);
        *(float4*)&yv[0]  = *(const float4*)(y + gp);
        *(float4*)&yv[4]  = *(const float4*)(y + gp + 4);
        *(float4*)&yv[8]  = *(const float4*)(y + gp + 8);
        *(float4*)&yv[12] = *(const float4*)(y + gp + 12);
        float sm = 0.f, sq = 0.f;
#pragma unroll
        for (int i2 = 0; i2 < 16; i2++) { sm += xv[i2]; sq += xv[i2] * xv[i2]; }
#pragma unroll
        for (int msk = 1; msk < 8; msk <<= 1) {
            sm += __shfl_xor(sm, msk, 64); sq += __shfl_xor(sq, msk, 64);
        }
        const float mu = sm * (1.f / 128.f);
        const float ri = rsqrtf(sq * (1.f / 128.f) - mu * mu + 1e-5f);
        float w1[16], b1[16];
        *(float4*)&w1[0]  = *(const float4*)(n1_w + c16);
        *(float4*)&w1[4]  = *(const float4*)(n1_w + c16 + 4);
        *(float4*)&w1[8]  = *(const float4*)(n1_w + c16 + 8);
        *(float4*)&w1[12] = *(const float4*)(n1_w + c16 + 12);
        *(float4*)&b1[0]  = *(const float4*)(n1_b + c16);
        *(float4*)&b1[4]  = *(const float4*)(n1_b + c16 + 4);
        *(float4*)&b1[8]  = *(const float4*)(n1_b + c16 + 8);
        *(float4*)&b1[12] = *(const float4*)(n1_b + c16 + 12);
        uint4 o0, o1, p0, p1;
        o0.x = pack2((xv[0] - mu) * ri * w1[0] + b1[0],   (xv[1] - mu) * ri * w1[1] + b1[1]);
        o0.y = pack2((xv[2] - mu) * ri * w1[2] + b1[2],   (xv[3] - mu) * ri * w1[3] + b1[3]);
        o0.z = pack2((xv[4] - mu) * ri * w1[4] + b1[4],   (xv[5] - mu) * ri * w1[5] + b1[5]);
        o0.w = pack2((xv[6] - mu) * ri * w1[6] + b1[6],   (xv[7] - mu) * ri * w1[7] + b1[7]);
        o1.x = pack2((xv[8] - mu) * ri * w1[8] + b1[8],   (xv[9] - mu) * ri * w1[9] + b1[9]);
        o1.y = pack2((xv[10] - mu) * ri * w1[10] + b1[10], (xv[11] - mu) * ri * w1[11] + b1[11]);
        o1.z = pack2((xv[12] - mu) * ri * w1[12] + b1[12], (xv[13] - mu) * ri * w1[13] + b1[13]);
        o1.w = pack2((xv[14] - mu) * ri * w1[14] + b1[14], (xv[15] - mu) * ri * w1[15] + b1[15]);
        p0.x = pack2(yv[0], yv[1]);   p0.y = pack2(yv[2], yv[3]);
        p0.z = pack2(yv[4], yv[5]);   p0.w = pack2(yv[6], yv[7]);
        p1.x = pack2(yv[8], yv[9]);   p1.y = pack2(yv[10], yv[11]);
        p1.z = pack2(yv[12], yv[13]); p1.w = pack2(yv[14], yv[15]);
        *(uint4*)&xn[r][c16] = o0;
        *(uint4*)&xn[r][c16 + 8] = o1;
        *(uint4*)&yl[r][c16] = p0;
        *(uint4*)&yl[r][c16 + 8] = p1;
    }
    __syncthreads();
    const int wave = t >> 6, lane = t & 63, quad = lane >> 4, l15 = lane & 15;
    const float scale = 0.1767766952966369f;   // 1/sqrt(32)
    // ---- qv GEMM: 16 n-tiles over 8 waves = 2 each; B-frags converted at
    //      load (fp32, L2-hit), reused x4 m-tiles ----
    {
        bf16x8 aA[4][4];
#pragma unroll
        for (int m = 0; m < 4; m++)
#pragma unroll
            for (int kt = 0; kt < 4; kt++)
                aA[m][kt] = *(const bf16x8*)&xn[m * 16 + l15][kt * 32 + quad * 8];
#pragma unroll
        for (int s = 0; s < 2; s++) {
            const int n = (wave * 2 + s) * 16 + l15;
            bf16x8 w[4];
#pragma unroll
            for (int kt = 0; kt < 4; kt++)
                w[kt] = ldw8c(qv_w + (size_t)n * C + kt * 32 + quad * 8);
            f32x4 acc[4];
#pragma unroll
            for (int m = 0; m < 4; m++) acc[m] = (f32x4){0.f, 0.f, 0.f, 0.f};
#pragma unroll
            for (int m = 0; m < 4; m++)
#pragma unroll
                for (int kt = 0; kt < 4; kt++)
                    acc[m] = __builtin_amdgcn_mfma_f32_16x16x32_bf16(aA[m][kt], w[kt], acc[m], 0, 0, 0);
            const float bias = qv_b[n];
            if (wave * 2 + s < 8) {
#pragma unroll
                for (int m = 0; m < 4; m++)
#pragma unroll
                    for (int r = 0; r < 4; r++)
                        qb[(size_t)(pix0 + m * 16 + quad * 4 + r) * C + n] =
                            __float2bfloat16((acc[m][r] + bias) * scale);
            } else {
#pragma unroll
                for (int m = 0; m < 4; m++)
#pragma unroll
                    for (int r = 0; r < 4; r++)
                        vb[(size_t)(pix0 + m * 16 + quad * 4 + r) * C + (n - C)] =
                            __float2bfloat16(acc[m][r] + bias);
            }
        }
    }
    // ---- k GEMM: 8 n-tiles over 8 waves = 1 each; same pattern ----
    {
        bf16x8 aY[4][4];
#pragma unroll
        for (int m = 0; m < 4; m++)
#pragma unroll
            for (int kt = 0; kt < 4; kt++)
                aY[m][kt] = *(const bf16x8*)&yl[m * 16 + l15][kt * 32 + quad * 8];
        const int n = wave * 16 + l15;
        bf16x8 w[4];
#pragma unroll
        for (int kt = 0; kt < 4; kt++)
            w[kt] = ldw8c(k_w + (size_t)n * C + kt * 32 + quad * 8);
        f32x4 acc[4];
#pragma unroll
        for (int m = 0; m < 4; m++) acc[m] = (f32x4){0.f, 0.f, 0.f, 0.f};
#pragma unroll
        for (int m = 0; m < 4; m++)
#pragma unroll
            for (int kt = 0; kt < 4; kt++)
                acc[m] = __builtin_amdgcn_mfma_f32_16x16x32_bf16(aY[m][kt], w[kt], acc[m], 0, 0, 0);
        const float bias = k_b[n];
#pragma unroll
        for (int m = 0; m < 4; m++)
#pragma unroll
            for (int r = 0; r < 4; r++)
                kb[(size_t)(pix0 + m * 16 + quad * 4 + r) * C + n] =
                    __float2bfloat16(acc[m][r] + bias);
    }
}

// ---------- kernel 2: fused attn + proj + residual + LN2 + MLP, 64 px ------
// (byte-identical to R13's proven 43.6us version)
__global__ __launch_bounds__(512, 2) void k_fam(
    const bf16* __restrict__ qb, const bf16* __restrict__ kb,
    const bf16* __restrict__ vb, const float* __restrict__ rpb,
    const float* __restrict__ x,
    const short* __restrict__ wproj, const float* __restrict__ proj_b,
    const float* __restrict__ n2_w, const float* __restrict__ n2_b,
    const short* __restrict__ wfc1, const float* __restrict__ fc1_b,
    const short* __restrict__ wfc2, const float* __restrict__ fc2_b,
    float* __restrict__ out) {
    __shared__ short SH[67104];           // 134,208 B
    short* const KU  = SH;                // 196 x 132  [0, 25872)
    short* const VU  = SH + 25872;        // 196 x 132  [25872, 51744)
    short* const Pb  = SH + 51744;        // 8 x 16 x 120 [51744, 67104)
    short* const aoL = SH;                // 64 x 132 (post-PV)
    short* const xnb = SH + 8448;         // 64 x 132
    short* const hb  = SH + 16896;        // 64 x 520 -> [16896, 50176)
    short* const x1b = SH + 51744;        // 64 x 132 (over Pb)
    const int t = threadIdx.x;
    const int wave = t >> 6, lane = t & 63, quad = lane >> 4, l15 = lane & 15;
    const int h = wave & 3, mt = wave >> 2;
    const int p = wave & 1, g = wave >> 1;
    const int tile = (blockIdx.x & 7) * 32 + (blockIdx.x >> 3);   // XCD swizzle
    const int i0 = (tile >> 4) * 8, j0 = (tile & 15) * 8;
    const int rs = min(max(i0 - 3, 0), 114);
    const int cs2 = min(max(j0 - 3, 0), 114);
    const int n_0 = (2 * g) * 16 + l15, n_1 = (2 * g + 1) * 16 + l15;
    // ---- prefetch: Q frags (attention mapping) + fp32 residual (MLP map) ----
    bf16x8 aQv[2];
#pragma unroll
    for (int u = 0; u < 2; u++) {
        const int q = mt * 2 + u;
        const int iq = i0 + (q >> 1) * 4, jq = j0 + (q & 1) * 4;
        const int pA = (iq + (l15 >> 2)) * HW + jq + (l15 & 3);
        aQv[u] = *(const bf16x8*)(qb + (size_t)pA * C + h * HD + quad * 8);
    }
    float xres[2][2][4];
#pragma unroll
    for (int u = 0; u < 2; u++) {
        const int qm = 2 * p + u;
        const int ib = i0 + (qm >> 1) * 4 + quad, jb = j0 + (qm & 1) * 4;
#pragma unroll
        for (int r = 0; r < 4; r++) {
            const size_t pp = (size_t)(ib * HW + jb + r) * C;
            xres[u][0][r] = x[pp + n_0];
            xres[u][1][r] = x[pp + n_1];
        }
    }
    // ---- stage halo K,V (196 rows x 16 segs), incremental /14 ----
    {
        const int seg = t & 15, r0 = t >> 4;          // r0 in 0..31
        int q14 = (r0 >= 28) ? 2 : (r0 >= 14 ? 1 : 0);
        int m14 = r0 - 14 * q14;
        int r = r0;
#pragma unroll
        for (int it = 0; it < 7; it++) {
            if (r < 196) {
                const size_t gp = (size_t)((rs + q14) * HW + (cs2 + m14)) * C + seg * 8;
                *(uint4*)&KU[r * 132 + seg * 8] = *(const uint4*)(kb + gp);
                *(uint4*)&VU[r * 132 + seg * 8] = *(const uint4*)(vb + gp);
            }
            r += 32; q14 += 2; m14 += 4;
            if (m14 >= 14) { m14 -= 14; q14 += 1; }
        }
    }
    // neighbor (nr,nc) for nb = nt*16 + l15 (shared across m-tiles)
    int nrA[7], ncA[7];
    {
        int nr = (l15 >= 10) ? 1 : 0;
        int nc = l15 - ((l15 >= 10) ? 10 : 0);
#pragma unroll
        for (int nt = 0; nt < 7; nt++) {
            nrA[nt] = nr; ncA[nt] = nc;
            nc += 6; nr += 1;
            if (nc >= 10) { nc -= 10; nr += 1; }
        }
    }
    __syncthreads();   // B1: halo staged
    // ---- attention: per wave, sequential over its 2 m-tiles ----
    const float* rpbh = rpb + h * 169;
    f32x4 Oacc[2][2];
#pragma unroll
    for (int u = 0; u < 2; u++) {
        Oacc[u][0] = (f32x4){0.f, 0.f, 0.f, 0.f};
        Oacc[u][1] = (f32x4){0.f, 0.f, 0.f, 0.f};
    }
#pragma unroll
    for (int u = 0; u < 2; u++) {
        const int q = mt * 2 + u;
        const int iq = i0 + (q >> 1) * 4, jq = j0 + (q & 1) * 4;
        const int rq = min(max(iq - 3, 0), 118), cq = min(max(jq - 3, 0), 118);
        const int vbase = (rq - rs) * 14 + (cq - cs2);
        // QK^T: 7 nt tiles over the m-tile's 100-row sub-union
        f32x4 S[7];
#pragma unroll
        for (int nt = 0; nt < 7; nt++) {
            const int lr = min(vbase + nrA[nt] * 14 + ncA[nt], 195);
            const bf16x8 bK = *(const bf16x8*)&KU[lr * 132 + h * HD + quad * 8];
            f32x4 z = {0.f, 0.f, 0.f, 0.f};
            S[nt] = __builtin_amdgcn_mfma_f32_16x16x32_bf16(aQv[u], bK, z, 0, 0, 0);
        }
        // softmax
        float smx[4];
#pragma unroll
        for (int r = 0; r < 4; r++) {
            const int i = iq + quad, j = jq + r;
            const int shi = min(max(i - 3, 0), 121);
            const int swj = min(max(j - 3, 0), 121);
            float best = -1e30f;
#pragma unroll
            for (int nt = 0; nt < 7; nt++) {
                const int ai = rq + nrA[nt], aj = cq + ncA[nt];
                const bool vnb = (nt < 6) | (l15 < 4);          // nb < 100
                const bool valid = vnb & (ai >= shi) & (ai <= shi + 6) & (aj >= swj) & (aj <= swj + 6);
                const int ri = min(max(ai - i + 6, 0), 12);
                const int rj = min(max(aj - j + 6, 0), 12);
                const float v = valid ? (S[nt][r] + rpbh[ri * 13 + rj]) : -1e30f;
                S[nt][r] = v;
                best = fmaxf(best, v);
            }
            for (int msk = 1; msk < 16; msk <<= 1) best = fmaxf(best, __shfl_xor(best, msk, 64));
            float s = 0.f;
#pragma unroll
            for (int nt = 0; nt < 7; nt++) {
                const float e = __expf(S[nt][r] - best);
                S[nt][r] = e;
                s += e;
            }
            for (int msk = 1; msk < 16; msk <<= 1) s += __shfl_xor(s, msk, 64);
            smx[r] = 1.f / s;
        }
        // P write (own-wave rows; Pb region independent of K/V)
#pragma unroll
        for (int r = 0; r < 4; r++) {
            short* prow = &Pb[(wave * 16 + quad * 4 + r) * 120];
#pragma unroll
            for (int nt = 0; nt < 7; nt++)
                prow[nt * 16 + l15] = f2bs(S[nt][r] * smx[r]);
        }
        // PV: kt 0..2 full (k<=95 in sub-union); kt=3 peeled
#pragma unroll
        for (int kt = 0; kt < 3; kt++) {
            const bf16x8 aP = *(const bf16x8*)&Pb[(wave * 16 + l15) * 120 + kt * 32 + quad * 8];
            const int kbase = kt * 32 + quad * 8;
            int kr = (kbase * 205) >> 11;
            int kc = kbase - 10 * kr;
            int sidx = vbase + kr * 14 + kc;
            int lvr[8];
#pragma unroll
            for (int jj = 0; jj < 8; jj++) {
                lvr[jj] = sidx;
                kc++; sidx++;
                if (kc >= 10) { kc = 0; sidx += 4; }
            }
#pragma unroll
            for (int nt2 = 0; nt2 < 2; nt2++) {
                const int ch = h * HD + nt2 * 16 + l15;
                bf16x8 bV;
#pragma unroll
                for (int jj = 0; jj < 8; jj++) bV[jj] = VU[lvr[jj] * 132 + ch];
                Oacc[u][nt2] = __builtin_amdgcn_mfma_f32_16x16x32_bf16(aP, bV, Oacc[u][nt2], 0, 0, 0);
            }
        }
        {   // kt=3: k 96..127; only quad 0 carries data (P cols 100..111 = 0)
            bf16x8 aP = {0, 0, 0, 0, 0, 0, 0, 0};
            if (quad < 2) aP = *(const bf16x8*)&Pb[(wave * 16 + l15) * 120 + 96 + quad * 8];
#pragma unroll
            for (int nt2 = 0; nt2 < 2; nt2++) {
                const int ch = h * HD + nt2 * 16 + l15;
                bf16x8 bV = {0, 0, 0, 0, 0, 0, 0, 0};
                if (quad == 0) {
#pragma unroll
                    for (int jj = 0; jj < 8; jj++) {
                        const int kc3 = (6 + jj > 9) ? 9 : 6 + jj;
                        bV[jj] = VU[(vbase + 126 + kc3) * 132 + ch];   // row 9
                    }
                }
                Oacc[u][nt2] = __builtin_amdgcn_mfma_f32_16x16x32_bf16(aP, bV, Oacc[u][nt2], 0, 0, 0);
            }
        }
    }
    // ---- wproj prefetch (MLP mapping) before the barrier drain ----
    bf16x8 wp0[4], wp1[4];
#pragma unroll
    for (int kt = 0; kt < 4; kt++) {
        wp0[kt] = *(const bf16x8*)&wproj[n_0 * C + kt * 32 + quad * 8];
        wp1[kt] = *(const bf16x8*)&wproj[n_1 * C + kt * 32 + quad * 8];
    }
    __syncthreads();   // B2: K/V/P reads done; stage region dead
    // ---- ao -> aoL (64 x 132) ----
#pragma unroll
    for (int u = 0; u < 2; u++) {
        const int q = mt * 2 + u;
#pragma unroll
        for (int r = 0; r < 4; r++) {
            const int m = q * 16 + quad * 4 + r;
            aoL[m * 132 + h * HD + l15] = f2bs(Oacc[u][0][r]);
            aoL[m * 132 + h * HD + 16 + l15] = f2bs(Oacc[u][1][r]);
        }
    }
    __syncthreads();   // B3
    // ---- proj + fp32 residual -> x1b (+ fp32 regs) ----
    float x1f[2][2][4];
    {
        bf16x8 aO[2][4];
#pragma unroll
        for (int u = 0; u < 2; u++)
#pragma unroll
            for (int kt = 0; kt < 4; kt++)
                aO[u][kt] = *(const bf16x8*)&aoL[((2 * p + u) * 16 + l15) * 132 + kt * 32 + quad * 8];
        f32x4 pa[2][2];
        pa[0][0] = (f32x4){0.f, 0.f, 0.f, 0.f}; pa[0][1] = (f32x4){0.f, 0.f, 0.f, 0.f};
        pa[1][0] = (f32x4){0.f, 0.f, 0.f, 0.f}; pa[1][1] = (f32x4){0.f, 0.f, 0.f, 0.f};
#pragma unroll
        for (int kt = 0; kt < 4; kt++) {
            pa[0][0] = __builtin_amdgcn_mfma_f32_16x16x32_bf16(aO[0][kt], wp0[kt], pa[0][0], 0, 0, 0);
            pa[0][1] = __builtin_amdgcn_mfma_f32_16x16x32_bf16(aO[0][kt], wp1[kt], pa[0][1], 0, 0, 0);
            pa[1][0] = __builtin_amdgcn_mfma_f32_16x16x32_bf16(aO[1][kt], wp0[kt], pa[1][0], 0, 0, 0);
            pa[1][1] = __builtin_amdgcn_mfma_f32_16x16x32_bf16(aO[1][kt], wp1[kt], pa[1][1], 0, 0, 0);
        }
        const float b0s = proj_b[n_0], b1s = proj_b[n_1];
#pragma unroll
        for (int u = 0; u < 2; u++) {
#pragma unroll
            for (int r = 0; r < 4; r++) {
                const int m = (2 * p + u) * 16 + quad * 4 + r;
                const float v0 = xres[u][0][r] + pa[u][0][r] + b0s;
                const float v1 = xres[u][1][r] + pa[u][1][r] + b1s;
                x1f[u][0][r] = v0; x1f[u][1][r] = v1;
                x1b[m * 132 + n_0] = f2bs(v0);
                x1b[m * 132 + n_1] = f2bs(v1);
            }
        }
    }
    __syncthreads();   // B4
    // ---- LN2 stats + xn write, fused (row = t>>3, 8 thr/row x 16 ch) ----
    {
        const int row = t >> 3, c16 = (t & 7) * 16;
        float xv[16];
        {
            const uint4 d0 = *(const uint4*)&x1b[row * 132 + c16];
            const uint4 d1 = *(const uint4*)&x1b[row * 132 + c16 + 8];
            const unsigned int w[8] = {d0.x, d0.y, d0.z, d0.w, d1.x, d1.y, d1.z, d1.w};
#pragma unroll
            for (int i2 = 0; i2 < 8; i2++) {
                xv[2 * i2]     = bs2f((short)(w[i2] & 0xffff));
                xv[2 * i2 + 1] = bs2f((short)(w[i2] >> 16));
            }
        }
        float sm = 0.f, sq = 0.f;
#pragma unroll
        for (int i2 = 0; i2 < 16; i2++) { sm += xv[i2]; sq += xv[i2] * xv[i2]; }
#pragma unroll
        for (int msk = 1; msk < 8; msk <<= 1) {
            sm += __shfl_xor(sm, msk, 64); sq += __shfl_xor(sq, msk, 64);
        }
        const float mu = sm * (1.f / 128.f);
        const float ri = rsqrtf(sq * (1.f / 128.f) - mu * mu + 1e-5f);
        float w2[16], b2[16];
        *(float4*)&w2[0]  = *(const float4*)(n2_w + c16);
        *(float4*)&w2[4]  = *(const float4*)(n2_w + c16 + 4);
        *(float4*)&w2[8]  = *(const float4*)(n2_w + c16 + 8);
        *(float4*)&w2[12] = *(const float4*)(n2_w + c16 + 12);
        *(float4*)&b2[0]  = *(const float4*)(n2_b + c16);
        *(float4*)&b2[4]  = *(const float4*)(n2_b + c16 + 4);
        *(float4*)&b2[8]  = *(const float4*)(n2_b + c16 + 8);
        *(float4*)&b2[12] = *(const float4*)(n2_b + c16 + 12);
        uint4 o0, o1;
        o0.x = pack2((xv[0] - mu) * ri * w2[0] + b2[0],   (xv[1] - mu) * ri * w2[1] + b2[1]);
        o0.y = pack2((xv[2] - mu) * ri * w2[2] + b2[2],   (xv[3] - mu) * ri * w2[3] + b2[3]);
        o0.z = pack2((xv[4] - mu) * ri * w2[4] + b2[4],   (xv[5] - mu) * ri * w2[5] + b2[5]);
        o0.w = pack2((xv[6] - mu) * ri * w2[6] + b2[6],   (xv[7] - mu) * ri * w2[7] + b2[7]);
        o1.x = pack2((xv[8] - mu) * ri * w2[8] + b2[8],   (xv[9] - mu) * ri * w2[9] + b2[9]);
        o1.y = pack2((xv[10] - mu) * ri * w2[10] + b2[10], (xv[11] - mu) * ri * w2[11] + b2[11]);
        o1.z = pack2((xv[12] - mu) * ri * w2[12] + b2[12], (xv[13] - mu) * ri * w2[13] + b2[13]);
        o1.w = pack2((xv[14] - mu) * ri * w2[14] + b2[14], (xv[15] - mu) * ri * w2[15] + b2[15]);
        *(uint4*)&xnb[row * 132 + c16] = o0;
        *(uint4*)&xnb[row * 132 + c16 + 8] = o1;
    }
    __syncthreads();   // B5
    // ---- fc1 + gelu -> hb: m-pair p x n-tiles g*8+a (weight reuse over m) --
    {
        bf16x8 aX[2][4];
#pragma unroll
        for (int u = 0; u < 2; u++)
#pragma unroll
            for (int kt = 0; kt < 4; kt++)
                aX[u][kt] = *(const bf16x8*)&xnb[((2 * p + u) * 16 + l15) * 132 + kt * 32 + quad * 8];
#pragma unroll
        for (int a = 0; a < 8; a++) {
            const int n = (g * 8 + a) * 16 + l15;
            f32x4 c0 = {0.f, 0.f, 0.f, 0.f}, c1 = {0.f, 0.f, 0.f, 0.f};
#pragma unroll
            for (int kt = 0; kt < 4; kt++) {
                const bf16x8 bw = *(const bf16x8*)&wfc1[n * C + kt * 32 + quad * 8];
                c0 = __builtin_amdgcn_mfma_f32_16x16x32_bf16(aX[0][kt], bw, c0, 0, 0, 0);
                c1 = __builtin_amdgcn_mfma_f32_16x16x32_bf16(aX[1][kt], bw, c1, 0, 0, 0);
            }
            const float bias = fc1_b[n];
#pragma unroll
            for (int r = 0; r < 4; r++) {
                const int m0 = (2 * p) * 16 + quad * 4 + r;
                hb[m0 * 520 + n] = f2bs(gelu_f(c0[r] + bias));
                hb[(m0 + 16) * 520 + n] = f2bs(gelu_f(c1[r] + bias));
            }
        }
    }
    __syncthreads();   // B6
    // ---- fc2 + fp32 residual (regs) -> out ----
    {
        f32x4 f00 = {0.f, 0.f, 0.f, 0.f}, f01 = {0.f, 0.f, 0.f, 0.f};
        f32x4 f10 = {0.f, 0.f, 0.f, 0.f}, f11 = {0.f, 0.f, 0.f, 0.f};
#pragma unroll
        for (int kt = 0; kt < 16; kt++) {
            const bf16x8 a0 = *(const bf16x8*)&hb[((2 * p) * 16 + l15) * 520 + kt * 32 + quad * 8];
            const bf16x8 a1 = *(const bf16x8*)&hb[((2 * p + 1) * 16 + l15) * 520 + kt * 32 + quad * 8];
            const bf16x8 w0 = *(const bf16x8*)&wfc2[n_0 * 512 + kt * 32 + quad * 8];
            const bf16x8 w1 = *(const bf16x8*)&wfc2[n_1 * 512 + kt * 32 + quad * 8];
            f00 = __builtin_amdgcn_mfma_f32_16x16x32_bf16(a0, w0, f00, 0, 0, 0);
            f01 = __builtin_amdgcn_mfma_f32_16x16x32_bf16(a0, w1, f01, 0, 0, 0);
            f10 = __builtin_amdgcn_mfma_f32_16x16x32_bf16(a1, w0, f10, 0, 0, 0);
            f11 = __builtin_amdgcn_mfma_f32_16x16x32_bf16(a1, w1, f11, 0, 0, 0);
        }
        const float b0s = fc2_b[n_0], b1s = fc2_b[n_1];
#pragma unroll
        for (int u = 0; u < 2; u++) {
            const int qm = 2 * p + u;
            const int ib = i0 + (qm >> 1) * 4 + quad, jb = j0 + (qm & 1) * 4;
#pragma unroll
            for (int r = 0; r < 4; r++) {
                const size_t pp = (size_t)(ib * HW + jb + r) * C;
                const float v0 = (u ? f10[r] : f00[r]) + b0s + x1f[u][0][r];
                const float v1 = (u ? f11[r] : f01[r]) + b1s + x1f[u][1][r];
                out[pp + n_0] = v0;
                out[pp + n_1] = v1;
            }
        }
    }
}

extern "C" void kernel_launch(void* const* d_in, const int* in_sizes, int n_in,
                              void* d_out, int out_size, void* d_ws, size_t ws_size,
                              hipStream_t stream) {
    const float* x      = (const float*)d_in[0];
    const float* y      = (const float*)d_in[1];
    const float* qv_w   = (const float*)d_in[2];
    const float* qv_b   = (const float*)d_in[3];
    const float* k_w    = (const float*)d_in[4];
    const float* k_b    = (const float*)d_in[5];
    const float* rpb    = (const float*)d_in[6];
    const float* proj_w = (const float*)d_in[7];
    const float* proj_b = (const float*)d_in[8];
    const float* n1_w   = (const float*)d_in[9];
    const float* n1_b   = (const float*)d_in[10];
    const float* n2_w   = (const float*)d_in[11];
    const float* n2_b   = (const float*)d_in[12];
    const float* fc1_w  = (const float*)d_in[13];
    const float* fc1_b  = (const float*)d_in[14];
    const float* fc2_w  = (const float*)d_in[15];
    const float* fc2_b  = (const float*)d_in[16];
    float* out = (float*)d_out;

    bf16* qb  = (bf16*)d_ws;
    bf16* vb  = qb + (size_t)N_PIX * C;
    bf16* kb  = vb + (size_t)N_PIX * C;
    short* wproj= (short*)(kb + (size_t)N_PIX * C); // 16384
    short* wfc1 = wproj + 16384;                    // 65536
    short* wfc2 = wfc1 + 65536;                     // 65536  (total ~12.6 MB)

    k_qkv<<<256, 512, 0, stream>>>(x, y, qv_w, qv_b, k_w, k_b, n1_w, n1_b,
                                   proj_w, fc1_w, fc2_w,
                                   qb, vb, kb, wproj, wfc1, wfc2);
    k_fam<<<256, 512, 0, stream>>>(qb, kb, vb, rpb, x, wproj, proj_b, n2_w, n2_b,
                                   wfc1, fc1_b, wfc2, fc2_b, out);
}

// Round 16
// 144.497 us; speedup vs baseline: 1.0061x; 1.0061x over previous
//
#include <hip/hip_runtime.h>
#include <hip/hip_bf16.h>

// CrossNATBlock2D: B=1, H=W=128, C=128, HEADS=4, HD=32, K=7  (fp32 I/O)
// R33: final revert to R30/R13 (verified 145.0us, passed). R32's grid-512
// k_qkv diverged under graph replay (unexplained, like R28's NaN) — two
// strikes on k_qkv geometry experiments; locking in the best verified state.
// k_qkv: wconv prologue + LDS-staged qv/k weights + LN1-fused staging,
// 64px/512thr. k_fam: 64px 8x8 tile, per-m-tile sub-union attention,
// 134KB LDS, proven 43.6us.

#define N_PIX 16384
#define C 128
#define HEADS 4
#define HD 32
#define HW 128

typedef __hip_bfloat16 bf16;
typedef __attribute__((ext_vector_type(8))) short bf16x8;
typedef __attribute__((ext_vector_type(4))) float f32x4;

__device__ __forceinline__ short f2bs(float f) {
    unsigned int r;
    asm("v_cvt_pk_bf16_f32 %0, %1, %2" : "=v"(r) : "v"(f), "v"(f));
    return (short)(r & 0xffff);
}
__device__ __forceinline__ unsigned int pack2(float a, float b) {
    unsigned int r;
    asm("v_cvt_pk_bf16_f32 %0, %1, %2" : "=v"(r) : "v"(a), "v"(b));
    return r;
}
__device__ __forceinline__ float bs2f(short s) {
    __hip_bfloat16_raw r; r.x = (unsigned short)s;
    return __bfloat162float(__hip_bfloat16(r));
}
__device__ __forceinline__ float gelu_f(float v) {
    const float z2 = v * (2.302236206f + 0.102943322f * v * v);
    return v / (1.f + exp2f(-z2));
}

// ---------- kernel 1: wconv prologue + LN1 + QV GEMM + K proj ----------
// 64 px/block, 512 thr, grid 256. Weights for own GEMMs staged in LDS.
__global__ __launch_bounds__(512, 2) void k_qkv(
    const float* __restrict__ x, const float* __restrict__ y,
    const float* __restrict__ qv_w, const float* __restrict__ qv_b,
    const float* __restrict__ k_w, const float* __restrict__ k_b,
    const float* __restrict__ n1_w, const float* __restrict__ n1_b,
    const float* __restrict__ proj_w, const float* __restrict__ fc1_w,
    const float* __restrict__ fc2_w,
    bf16* __restrict__ qb, bf16* __restrict__ vb, bf16* __restrict__ kb,
    short* __restrict__ wproj, short* __restrict__ wfc1,
    short* __restrict__ wfc2) {
    __shared__ short xn[64][136];         //  17,408 B
    __shared__ short yl[64][136];         //  17,408 B
    __shared__ short wqvL[256 * 136];     //  69,632 B
    __shared__ short wkL[128 * 136];      //  34,816 B   (total 139,264 B)
    const int t = threadIdx.x;
    const int pix0 = ((blockIdx.x & 7) * 32 + (blockIdx.x >> 3)) * 64;
    // ---- phase 0a: convert proj/fc1/fc2 -> ws (k_fam consumers only;
    //      disjoint global writes, no barrier needed, stream-ordered) ----
    {
        const int gi = blockIdx.x * 512 + t;          // 0..131071
        if (gi < 16384) wproj[gi] = f2bs(proj_w[gi]);
        if (gi < 65536) { wfc1[gi] = f2bs(fc1_w[gi]); wfc2[gi] = f2bs(fc2_w[gi]); }
    }
    // ---- phase 0b: stage qv/k weights fp32->bf16 into LDS (16-elem chunks;
    //      3072 chunks over 512 thr = 6 each) ----
#pragma unroll
    for (int it = 0; it < 6; it++) {
        const int c = t + it * 512;                   // 0..3071
        const bool isq = (c < 2048);
        const int cc = isq ? c : c - 2048;
        const float* src = (isq ? qv_w : k_w) + (size_t)cc * 16;
        short* dst = (isq ? wqvL : wkL) + (cc >> 3) * 136 + (cc & 7) * 16;
        float v[16];
        *(float4*)&v[0]  = *(const float4*)(src);
        *(float4*)&v[4]  = *(const float4*)(src + 4);
        *(float4*)&v[8]  = *(const float4*)(src + 8);
        *(float4*)&v[12] = *(const float4*)(src + 12);
        uint4 o0, o1;
        o0.x = pack2(v[0], v[1]);   o0.y = pack2(v[2], v[3]);
        o0.z = pack2(v[4], v[5]);   o0.w = pack2(v[6], v[7]);
        o1.x = pack2(v[8], v[9]);   o1.y = pack2(v[10], v[11]);
        o1.z = pack2(v[12], v[13]); o1.w = pack2(v[14], v[15]);
        *(uint4*)dst = o0;
        *(uint4*)(dst + 8) = o1;
    }
    // ---- phase 0c: fused stage + LN1 (thread owns row = t>>3, c16) ----
    {
        const int r = t >> 3, c16 = (t & 7) * 16;
        const size_t gp = (size_t)(pix0 + r) * C + c16;
        float xv[16], yv[16];
        *(float4*)&xv[0]  = *(const float4*)(x + gp);
        *(float4*)&xv[4]  = *(const float4*)(x + gp + 4);
        *(float4*)&xv[8]  = *(const float4*)(x + gp + 8);
        *(float4*)&xv[12] = *(const float4*)(x + gp + 12);
        *(float4*)&yv[0]  = *(const float4*)(y + gp);
        *(float4*)&yv[4]  = *(const float4*)(y + gp + 4);
        *(float4*)&yv[8]  = *(const float4*)(y + gp + 8);
        *(float4*)&yv[12] = *(const float4*)(y + gp + 12);
        float sm = 0.f, sq = 0.f;
#pragma unroll
        for (int i2 = 0; i2 < 16; i2++) { sm += xv[i2]; sq += xv[i2] * xv[i2]; }
#pragma unroll
        for (int msk = 1; msk < 8; msk <<= 1) {
            sm += __shfl_xor(sm, msk, 64); sq += __shfl_xor(sq, msk, 64);
        }
        const float mu = sm * (1.f / 128.f);
        const float ri = rsqrtf(sq * (1.f / 128.f) - mu * mu + 1e-5f);
        float w1[16], b1[16];
        *(float4*)&w1[0]  = *(const float4*)(n1_w + c16);
        *(float4*)&w1[4]  = *(const float4*)(n1_w + c16 + 4);
        *(float4*)&w1[8]  = *(const float4*)(n1_w + c16 + 8);
        *(float4*)&w1[12] = *(const float4*)(n1_w + c16 + 12);
        *(float4*)&b1[0]  = *(const float4*)(n1_b + c16);
        *(float4*)&b1[4]  = *(const float4*)(n1_b + c16 + 4);
        *(float4*)&b1[8]  = *(const float4*)(n1_b + c16 + 8);
        *(float4*)&b1[12] = *(const float4*)(n1_b + c16 + 12);
        uint4 o0, o1, p0, p1;
        o0.x = pack2((xv[0] - mu) * ri * w1[0] + b1[0],   (xv[1] - mu) * ri * w1[1] + b1[1]);
        o0.y = pack2((xv[2] - mu) * ri * w1[2] + b1[2],   (xv[3] - mu) * ri * w1[3] + b1[3]);
        o0.z = pack2((xv[4] - mu) * ri * w1[4] + b1[4],   (xv[5] - mu) * ri * w1[5] + b1[5]);
        o0.w = pack2((xv[6] - mu) * ri * w1[6] + b1[6],   (xv[7] - mu) * ri * w1[7] + b1[7]);
        o1.x = pack2((xv[8] - mu) * ri * w1[8] + b1[8],   (xv[9] - mu) * ri * w1[9] + b1[9]);
        o1.y = pack2((xv[10] - mu) * ri * w1[10] + b1[10], (xv[11] - mu) * ri * w1[11] + b1[11]);
        o1.z = pack2((xv[12] - mu) * ri * w1[12] + b1[12], (xv[13] - mu) * ri * w1[13] + b1[13]);
        o1.w = pack2((xv[14] - mu) * ri * w1[14] + b1[14], (xv[15] - mu) * ri * w1[15] + b1[15]);
        p0.x = pack2(yv[0], yv[1]);   p0.y = pack2(yv[2], yv[3]);
        p0.z = pack2(yv[4], yv[5]);   p0.w = pack2(yv[6], yv[7]);
        p1.x = pack2(yv[8], yv[9]);   p1.y = pack2(yv[10], yv[11]);
        p1.z = pack2(yv[12], yv[13]); p1.w = pack2(yv[14], yv[15]);
        *(uint4*)&xn[r][c16] = o0;
        *(uint4*)&xn[r][c16 + 8] = o1;
        *(uint4*)&yl[r][c16] = p0;
        *(uint4*)&yl[r][c16 + 8] = p1;
    }
    __syncthreads();
    const int wave = t >> 6, lane = t & 63, quad = lane >> 4, l15 = lane & 15;
    const float scale = 0.1767766952966369f;   // 1/sqrt(32)
    // ---- qv GEMM: 16 n-tiles over 8 waves = 2 each; B-frags from LDS ----
    {
        bf16x8 aA[4][4];
#pragma unroll
        for (int m = 0; m < 4; m++)
#pragma unroll
            for (int kt = 0; kt < 4; kt++)
                aA[m][kt] = *(const bf16x8*)&xn[m * 16 + l15][kt * 32 + quad * 8];
#pragma unroll
        for (int s = 0; s < 2; s++) {
            const int n = (wave * 2 + s) * 16 + l15;
            bf16x8 w[4];
#pragma unroll
            for (int kt = 0; kt < 4; kt++)
                w[kt] = *(const bf16x8*)&wqvL[n * 136 + kt * 32 + quad * 8];
            f32x4 acc[4];
#pragma unroll
            for (int m = 0; m < 4; m++) acc[m] = (f32x4){0.f, 0.f, 0.f, 0.f};
#pragma unroll
            for (int m = 0; m < 4; m++)
#pragma unroll
                for (int kt = 0; kt < 4; kt++)
                    acc[m] = __builtin_amdgcn_mfma_f32_16x16x32_bf16(aA[m][kt], w[kt], acc[m], 0, 0, 0);
            const float bias = qv_b[n];
            if (wave * 2 + s < 8) {
#pragma unroll
                for (int m = 0; m < 4; m++)
#pragma unroll
                    for (int r = 0; r < 4; r++)
                        qb[(size_t)(pix0 + m * 16 + quad * 4 + r) * C + n] =
                            __float2bfloat16((acc[m][r] + bias) * scale);
            } else {
#pragma unroll
                for (int m = 0; m < 4; m++)
#pragma unroll
                    for (int r = 0; r < 4; r++)
                        vb[(size_t)(pix0 + m * 16 + quad * 4 + r) * C + (n - C)] =
                            __float2bfloat16(acc[m][r] + bias);
            }
        }
    }
    // ---- k GEMM: 8 n-tiles over 8 waves = 1 each; B-frags from LDS ----
    {
        bf16x8 aY[4][4];
#pragma unroll
        for (int m = 0; m < 4; m++)
#pragma unroll
            for (int kt = 0; kt < 4; kt++)
                aY[m][kt] = *(const bf16x8*)&yl[m * 16 + l15][kt * 32 + quad * 8];
        const int n = wave * 16 + l15;
        bf16x8 w[4];
#pragma unroll
        for (int kt = 0; kt < 4; kt++)
            w[kt] = *(const bf16x8*)&wkL[n * 136 + kt * 32 + quad * 8];
        f32x4 acc[4];
#pragma unroll
        for (int m = 0; m < 4; m++) acc[m] = (f32x4){0.f, 0.f, 0.f, 0.f};
#pragma unroll
        for (int m = 0; m < 4; m++)
#pragma unroll
            for (int kt = 0; kt < 4; kt++)
                acc[m] = __builtin_amdgcn_mfma_f32_16x16x32_bf16(aY[m][kt], w[kt], acc[m], 0, 0, 0);
        const float bias = k_b[n];
#pragma unroll
        for (int m = 0; m < 4; m++)
#pragma unroll
            for (int r = 0; r < 4; r++)
                kb[(size_t)(pix0 + m * 16 + quad * 4 + r) * C + n] =
                    __float2bfloat16(acc[m][r] + bias);
    }
}

// ---------- kernel 2: fused attn + proj + residual + LN2 + MLP, 64 px ------
// (byte-identical to R12's proven 44.6us version)
__global__ __launch_bounds__(512, 2) void k_fam(
    const bf16* __restrict__ qb, const bf16* __restrict__ kb,
    const bf16* __restrict__ vb, const float* __restrict__ rpb,
    const float* __restrict__ x,
    const short* __restrict__ wproj, const float* __restrict__ proj_b,
    const float* __restrict__ n2_w, const float* __restrict__ n2_b,
    const short* __restrict__ wfc1, const float* __restrict__ fc1_b,
    const short* __restrict__ wfc2, const float* __restrict__ fc2_b,
    float* __restrict__ out) {
    __shared__ short SH[67104];           // 134,208 B
    short* const KU  = SH;                // 196 x 132  [0, 25872)
    short* const VU  = SH + 25872;        // 196 x 132  [25872, 51744)
    short* const Pb  = SH + 51744;        // 8 x 16 x 120 [51744, 67104)
    short* const aoL = SH;                // 64 x 132 (post-PV)
    short* const xnb = SH + 8448;         // 64 x 132
    short* const hb  = SH + 16896;        // 64 x 520 -> [16896, 50176)
    short* const x1b = SH + 51744;        // 64 x 132 (over Pb)
    const int t = threadIdx.x;
    const int wave = t >> 6, lane = t & 63, quad = lane >> 4, l15 = lane & 15;
    const int h = wave & 3, mt = wave >> 2;
    const int p = wave & 1, g = wave >> 1;
    const int tile = (blockIdx.x & 7) * 32 + (blockIdx.x >> 3);   // XCD swizzle
    const int i0 = (tile >> 4) * 8, j0 = (tile & 15) * 8;
    const int rs = min(max(i0 - 3, 0), 114);
    const int cs2 = min(max(j0 - 3, 0), 114);
    const int n_0 = (2 * g) * 16 + l15, n_1 = (2 * g + 1) * 16 + l15;
    // ---- prefetch: Q frags (attention mapping) + fp32 residual (MLP map) ----
    bf16x8 aQv[2];
#pragma unroll
    for (int u = 0; u < 2; u++) {
        const int q = mt * 2 + u;
        const int iq = i0 + (q >> 1) * 4, jq = j0 + (q & 1) * 4;
        const int pA = (iq + (l15 >> 2)) * HW + jq + (l15 & 3);
        aQv[u] = *(const bf16x8*)(qb + (size_t)pA * C + h * HD + quad * 8);
    }
    float xres[2][2][4];
#pragma unroll
    for (int u = 0; u < 2; u++) {
        const int qm = 2 * p + u;
        const int ib = i0 + (qm >> 1) * 4 + quad, jb = j0 + (qm & 1) * 4;
#pragma unroll
        for (int r = 0; r < 4; r++) {
            const size_t pp = (size_t)(ib * HW + jb + r) * C;
            xres[u][0][r] = x[pp + n_0];
            xres[u][1][r] = x[pp + n_1];
        }
    }
    // ---- stage halo K,V (196 rows x 16 segs), incremental /14 ----
    {
        const int seg = t & 15, r0 = t >> 4;          // r0 in 0..31
        int q14 = (r0 >= 28) ? 2 : (r0 >= 14 ? 1 : 0);
        int m14 = r0 - 14 * q14;
        int r = r0;
#pragma unroll
        for (int it = 0; it < 7; it++) {
            if (r < 196) {
                const size_t gp = (size_t)((rs + q14) * HW + (cs2 + m14)) * C + seg * 8;
                *(uint4*)&KU[r * 132 + seg * 8] = *(const uint4*)(kb + gp);
                *(uint4*)&VU[r * 132 + seg * 8] = *(const uint4*)(vb + gp);
            }
            r += 32; q14 += 2; m14 += 4;
            if (m14 >= 14) { m14 -= 14; q14 += 1; }
        }
    }
    // neighbor (nr,nc) for nb = nt*16 + l15 (shared across m-tiles)
    int nrA[7], ncA[7];
    {
        int nr = (l15 >= 10) ? 1 : 0;
        int nc = l15 - ((l15 >= 10) ? 10 : 0);
#pragma unroll
        for (int nt = 0; nt < 7; nt++) {
            nrA[nt] = nr; ncA[nt] = nc;
            nc += 6; nr += 1;
            if (nc >= 10) { nc -= 10; nr += 1; }
        }
    }
    __syncthreads();   // B1: halo staged
    // ---- attention: per wave, sequential over its 2 m-tiles ----
    const float* rpbh = rpb + h * 169;
    f32x4 Oacc[2][2];
#pragma unroll
    for (int u = 0; u < 2; u++) {
        Oacc[u][0] = (f32x4){0.f, 0.f, 0.f, 0.f};
        Oacc[u][1] = (f32x4){0.f, 0.f, 0.f, 0.f};
    }
#pragma unroll
    for (int u = 0; u < 2; u++) {
        const int q = mt * 2 + u;
        const int iq = i0 + (q >> 1) * 4, jq = j0 + (q & 1) * 4;
        const int rq = min(max(iq - 3, 0), 118), cq = min(max(jq - 3, 0), 118);
        const int vbase = (rq - rs) * 14 + (cq - cs2);
        // QK^T: 7 nt tiles over the m-tile's 100-row sub-union
        f32x4 S[7];
#pragma unroll
        for (int nt = 0; nt < 7; nt++) {
            const int lr = min(vbase + nrA[nt] * 14 + ncA[nt], 195);
            const bf16x8 bK = *(const bf16x8*)&KU[lr * 132 + h * HD + quad * 8];
            f32x4 z = {0.f, 0.f, 0.f, 0.f};
            S[nt] = __builtin_amdgcn_mfma_f32_16x16x32_bf16(aQv[u], bK, z, 0, 0, 0);
        }
        // softmax
        float smx[4];
#pragma unroll
        for (int r = 0; r < 4; r++) {
            const int i = iq + quad, j = jq + r;
            const int shi = min(max(i - 3, 0), 121);
            const int swj = min(max(j - 3, 0), 121);
            float best = -1e30f;
#pragma unroll
            for (int nt = 0; nt < 7; nt++) {
                const int ai = rq + nrA[nt], aj = cq + ncA[nt];
                const bool vnb = (nt < 6) | (l15 < 4);          // nb < 100
                const bool valid = vnb & (ai >= shi) & (ai <= shi + 6) & (aj >= swj) & (aj <= swj + 6);
                const int ri = min(max(ai - i + 6, 0), 12);
                const int rj = min(max(aj - j + 6, 0), 12);
                const float v = valid ? (S[nt][r] + rpbh[ri * 13 + rj]) : -1e30f;
                S[nt][r] = v;
                best = fmaxf(best, v);
            }
            for (int msk = 1; msk < 16; msk <<= 1) best = fmaxf(best, __shfl_xor(best, msk, 64));
            float s = 0.f;
#pragma unroll
            for (int nt = 0; nt < 7; nt++) {
                const float e = __expf(S[nt][r] - best);
                S[nt][r] = e;
                s += e;
            }
            for (int msk = 1; msk < 16; msk <<= 1) s += __shfl_xor(s, msk, 64);
            smx[r] = 1.f / s;
        }
        // P write (own-wave rows; Pb region independent of K/V)
#pragma unroll
        for (int r = 0; r < 4; r++) {
            short* prow = &Pb[(wave * 16 + quad * 4 + r) * 120];
#pragma unroll
            for (int nt = 0; nt < 7; nt++)
                prow[nt * 16 + l15] = f2bs(S[nt][r] * smx[r]);
        }
        // PV: kt 0..2 full (k<=95 in sub-union); kt=3 peeled
#pragma unroll
        for (int kt = 0; kt < 3; kt++) {
            const bf16x8 aP = *(const bf16x8*)&Pb[(wave * 16 + l15) * 120 + kt * 32 + quad * 8];
            const int kbase = kt * 32 + quad * 8;
            int kr = (kbase * 205) >> 11;
            int kc = kbase - 10 * kr;
            int sidx = vbase + kr * 14 + kc;
            int lvr[8];
#pragma unroll
            for (int jj = 0; jj < 8; jj++) {
                lvr[jj] = sidx;
                kc++; sidx++;
                if (kc >= 10) { kc = 0; sidx += 4; }
            }
#pragma unroll
            for (int nt2 = 0; nt2 < 2; nt2++) {
                const int ch = h * HD + nt2 * 16 + l15;
                bf16x8 bV;
#pragma unroll
                for (int jj = 0; jj < 8; jj++) bV[jj] = VU[lvr[jj] * 132 + ch];
                Oacc[u][nt2] = __builtin_amdgcn_mfma_f32_16x16x32_bf16(aP, bV, Oacc[u][nt2], 0, 0, 0);
            }
        }
        {   // kt=3: k 96..127; only quad 0 carries data (P cols 100..111 = 0)
            bf16x8 aP = {0, 0, 0, 0, 0, 0, 0, 0};
            if (quad < 2) aP = *(const bf16x8*)&Pb[(wave * 16 + l15) * 120 + 96 + quad * 8];
#pragma unroll
            for (int nt2 = 0; nt2 < 2; nt2++) {
                const int ch = h * HD + nt2 * 16 + l15;
                bf16x8 bV = {0, 0, 0, 0, 0, 0, 0, 0};
                if (quad == 0) {
#pragma unroll
                    for (int jj = 0; jj < 8; jj++) {
                        const int kc3 = (6 + jj > 9) ? 9 : 6 + jj;
                        bV[jj] = VU[(vbase + 126 + kc3) * 132 + ch];   // row 9
                    }
                }
                Oacc[u][nt2] = __builtin_amdgcn_mfma_f32_16x16x32_bf16(aP, bV, Oacc[u][nt2], 0, 0, 0);
            }
        }
    }
    // ---- wproj prefetch (MLP mapping) before the barrier drain ----
    bf16x8 wp0[4], wp1[4];
#pragma unroll
    for (int kt = 0; kt < 4; kt++) {
        wp0[kt] = *(const bf16x8*)&wproj[n_0 * C + kt * 32 + quad * 8];
        wp1[kt] = *(const bf16x8*)&wproj[n_1 * C + kt * 32 + quad * 8];
    }
    __syncthreads();   // B2: K/V/P reads done; stage region dead
    // ---- ao -> aoL (64 x 132) ----
#pragma unroll
    for (int u = 0; u < 2; u++) {
        const int q = mt * 2 + u;
#pragma unroll
        for (int r = 0; r < 4; r++) {
            const int m = q * 16 + quad * 4 + r;
            aoL[m * 132 + h * HD + l15] = f2bs(Oacc[u][0][r]);
            aoL[m * 132 + h * HD + 16 + l15] = f2bs(Oacc[u][1][r]);
        }
    }
    __syncthreads();   // B3
    // ---- proj + fp32 residual -> x1b (+ fp32 regs) ----
    float x1f[2][2][4];
    {
        bf16x8 aO[2][4];
#pragma unroll
        for (int u = 0; u < 2; u++)
#pragma unroll
            for (int kt = 0; kt < 4; kt++)
                aO[u][kt] = *(const bf16x8*)&aoL[((2 * p + u) * 16 + l15) * 132 + kt * 32 + quad * 8];
        f32x4 pa[2][2];
        pa[0][0] = (f32x4){0.f, 0.f, 0.f, 0.f}; pa[0][1] = (f32x4){0.f, 0.f, 0.f, 0.f};
        pa[1][0] = (f32x4){0.f, 0.f, 0.f, 0.f}; pa[1][1] = (f32x4){0.f, 0.f, 0.f, 0.f};
#pragma unroll
        for (int kt = 0; kt < 4; kt++) {
            pa[0][0] = __builtin_amdgcn_mfma_f32_16x16x32_bf16(aO[0][kt], wp0[kt], pa[0][0], 0, 0, 0);
            pa[0][1] = __builtin_amdgcn_mfma_f32_16x16x32_bf16(aO[0][kt], wp1[kt], pa[0][1], 0, 0, 0);
            pa[1][0] = __builtin_amdgcn_mfma_f32_16x16x32_bf16(aO[1][kt], wp0[kt], pa[1][0], 0, 0, 0);
            pa[1][1] = __builtin_amdgcn_mfma_f32_16x16x32_bf16(aO[1][kt], wp1[kt], pa[1][1], 0, 0, 0);
        }
        const float b0s = proj_b[n_0], b1s = proj_b[n_1];
#pragma unroll
        for (int u = 0; u < 2; u++) {
#pragma unroll
            for (int r = 0; r < 4; r++) {
                const int m = (2 * p + u) * 16 + quad * 4 + r;
                const float v0 = xres[u][0][r] + pa[u][0][r] + b0s;
                const float v1 = xres[u][1][r] + pa[u][1][r] + b1s;
                x1f[u][0][r] = v0; x1f[u][1][r] = v1;
                x1b[m * 132 + n_0] = f2bs(v0);
                x1b[m * 132 + n_1] = f2bs(v1);
            }
        }
    }
    __syncthreads();   // B4
    // ---- LN2 stats + xn write, fused (row = t>>3, 8 thr/row x 16 ch) ----
    {
        const int row = t >> 3, c16 = (t & 7) * 16;
        float xv[16];
        {
            const uint4 d0 = *(const uint4*)&x1b[row * 132 + c16];
            const uint4 d1 = *(const uint4*)&x1b[row * 132 + c16 + 8];
            const unsigned int w[8] = {d0.x, d0.y, d0.z, d0.w, d1.x, d1.y, d1.z, d1.w};
#pragma unroll
            for (int i2 = 0; i2 < 8; i2++) {
                xv[2 * i2]     = bs2f((short)(w[i2] & 0xffff));
                xv[2 * i2 + 1] = bs2f((short)(w[i2] >> 16));
            }
        }
        float sm = 0.f, sq = 0.f;
#pragma unroll
        for (int i2 = 0; i2 < 16; i2++) { sm += xv[i2]; sq += xv[i2] * xv[i2]; }
#pragma unroll
        for (int msk = 1; msk < 8; msk <<= 1) {
            sm += __shfl_xor(sm, msk, 64); sq += __shfl_xor(sq, msk, 64);
        }
        const float mu = sm * (1.f / 128.f);
        const float ri = rsqrtf(sq * (1.f / 128.f) - mu * mu + 1e-5f);
        float w2[16], b2[16];
        *(float4*)&w2[0]  = *(const float4*)(n2_w + c16);
        *(float4*)&w2[4]  = *(const float4*)(n2_w + c16 + 4);
        *(float4*)&w2[8]  = *(const float4*)(n2_w + c16 + 8);
        *(float4*)&w2[12] = *(const float4*)(n2_w + c16 + 12);
        *(float4*)&b2[0]  = *(const float4*)(n2_b + c16);
        *(float4*)&b2[4]  = *(const float4*)(n2_b + c16 + 4);
        *(float4*)&b2[8]  = *(const float4*)(n2_b + c16 + 8);
        *(float4*)&b2[12] = *(const float4*)(n2_b + c16 + 12);
        uint4 o0, o1;
        o0.x = pack2((xv[0] - mu) * ri * w2[0] + b2[0],   (xv[1] - mu) * ri * w2[1] + b2[1]);
        o0.y = pack2((xv[2] - mu) * ri * w2[2] + b2[2],   (xv[3] - mu) * ri * w2[3] + b2[3]);
        o0.z = pack2((xv[4] - mu) * ri * w2[4] + b2[4],   (xv[5] - mu) * ri * w2[5] + b2[5]);
        o0.w = pack2((xv[6] - mu) * ri * w2[6] + b2[6],   (xv[7] - mu) * ri * w2[7] + b2[7]);
        o1.x = pack2((xv[8] - mu) * ri * w2[8] + b2[8],   (xv[9] - mu) * ri * w2[9] + b2[9]);
        o1.y = pack2((xv[10] - mu) * ri * w2[10] + b2[10], (xv[11] - mu) * ri * w2[11] + b2[11]);
        o1.z = pack2((xv[12] - mu) * ri * w2[12] + b2[12], (xv[13] - mu) * ri * w2[13] + b2[13]);
        o1.w = pack2((xv[14] - mu) * ri * w2[14] + b2[14], (xv[15] - mu) * ri * w2[15] + b2[15]);
        *(uint4*)&xnb[row * 132 + c16] = o0;
        *(uint4*)&xnb[row * 132 + c16 + 8] = o1;
    }
    __syncthreads();   // B5
    // ---- fc1 + gelu -> hb: m-pair p x n-tiles g*8+a (weight reuse over m) --
    {
        bf16x8 aX[2][4];
#pragma unroll
        for (int u = 0; u < 2; u++)
#pragma unroll
            for (int kt = 0; kt < 4; kt++)
                aX[u][kt] = *(const bf16x8*)&xnb[((2 * p + u) * 16 + l15) * 132 + kt * 32 + quad * 8];
#pragma unroll
        for (int a = 0; a < 8; a++) {
            const int n = (g * 8 + a) * 16 + l15;
            f32x4 c0 = {0.f, 0.f, 0.f, 0.f}, c1 = {0.f, 0.f, 0.f, 0.f};
#pragma unroll
            for (int kt = 0; kt < 4; kt++) {
                const bf16x8 bw = *(const bf16x8*)&wfc1[n * C + kt * 32 + quad * 8];
                c0 = __builtin_amdgcn_mfma_f32_16x16x32_bf16(aX[0][kt], bw, c0, 0, 0, 0);
                c1 = __builtin_amdgcn_mfma_f32_16x16x32_bf16(aX[1][kt], bw, c1, 0, 0, 0);
            }
            const float bias = fc1_b[n];
#pragma unroll
            for (int r = 0; r < 4; r++) {
                const int m0 = (2 * p) * 16 + quad * 4 + r;
                hb[m0 * 520 + n] = f2bs(gelu_f(c0[r] + bias));
                hb[(m0 + 16) * 520 + n] = f2bs(gelu_f(c1[r] + bias));
            }
        }
    }
    __syncthreads();   // B6
    // ---- fc2 + fp32 residual (regs) -> out ----
    {
        f32x4 f00 = {0.f, 0.f, 0.f, 0.f}, f01 = {0.f, 0.f, 0.f, 0.f};
        f32x4 f10 = {0.f, 0.f, 0.f, 0.f}, f11 = {0.f, 0.f, 0.f, 0.f};
#pragma unroll
        for (int kt = 0; kt < 16; kt++) {
            const bf16x8 a0 = *(const bf16x8*)&hb[((2 * p) * 16 + l15) * 520 + kt * 32 + quad * 8];
            const bf16x8 a1 = *(const bf16x8*)&hb[((2 * p + 1) * 16 + l15) * 520 + kt * 32 + quad * 8];
            const bf16x8 w0 = *(const bf16x8*)&wfc2[n_0 * 512 + kt * 32 + quad * 8];
            const bf16x8 w1 = *(const bf16x8*)&wfc2[n_1 * 512 + kt * 32 + quad * 8];
            f00 = __builtin_amdgcn_mfma_f32_16x16x32_bf16(a0, w0, f00, 0, 0, 0);
            f01 = __builtin_amdgcn_mfma_f32_16x16x32_bf16(a0, w1, f01, 0, 0, 0);
            f10 = __builtin_amdgcn_mfma_f32_16x16x32_bf16(a1, w0, f10, 0, 0, 0);
            f11 = __builtin_amdgcn_mfma_f32_16x16x32_bf16(a1, w1, f11, 0, 0, 0);
        }
        const float b0s = fc2_b[n_0], b1s = fc2_b[n_1];
#pragma unroll
        for (int u = 0; u < 2; u++) {
            const int qm = 2 * p + u;
            const int ib = i0 + (qm >> 1) * 4 + quad, jb = j0 + (qm & 1) * 4;
#pragma unroll
            for (int r = 0; r < 4; r++) {
                const size_t pp = (size_t)(ib * HW + jb + r) * C;
                const float v0 = (u ? f10[r] : f00[r]) + b0s + x1f[u][0][r];
                const float v1 = (u ? f11[r] : f01[r]) + b1s + x1f[u][1][r];
                out[pp + n_0] = v0;
                out[pp + n_1] = v1;
            }
        }
    }
}

extern "C" void kernel_launch(void* const* d_in, const int* in_sizes, int n_in,
                              void* d_out, int out_size, void* d_ws, size_t ws_size,
                              hipStream_t stream) {
    const float* x      = (const float*)d_in[0];
    const float* y      = (const float*)d_in[1];
    const float* qv_w   = (const float*)d_in[2];
    const float* qv_b   = (const float*)d_in[3];
    const float* k_w    = (const float*)d_in[4];
    const float* k_b    = (const float*)d_in[5];
    const float* rpb    = (const float*)d_in[6];
    const float* proj_w = (const float*)d_in[7];
    const float* proj_b = (const float*)d_in[8];
    const float* n1_w   = (const float*)d_in[9];
    const float* n1_b   = (const float*)d_in[10];
    const float* n2_w   = (const float*)d_in[11];
    const float* n2_b   = (const float*)d_in[12];
    const float* fc1_w  = (const float*)d_in[13];
    const float* fc1_b  = (const float*)d_in[14];
    const float* fc2_w  = (const float*)d_in[15];
    const float* fc2_b  = (const float*)d_in[16];
    float* out = (float*)d_out;

    bf16* qb  = (bf16*)d_ws;
    bf16* vb  = qb + (size_t)N_PIX * C;
    bf16* kb  = vb + (size_t)N_PIX * C;
    short* wproj= (short*)(kb + (size_t)N_PIX * C); // 16384
    short* wfc1 = wproj + 16384;                    // 65536
    short* wfc2 = wfc1 + 65536;                     // 65536  (total ~12.6 MB)

    k_qkv<<<256, 512, 0, stream>>>(x, y, qv_w, qv_b, k_w, k_b, n1_w, n1_b,
                                   proj_w, fc1_w, fc2_w,
                                   qb, vb, kb, wproj, wfc1, wfc2);
    k_fam<<<256, 512, 0, stream>>>(qb, kb, vb, rpb, x, wproj, proj_b, n2_w, n2_b,
                                   wfc1, fc1_b, wfc2, fc2_b, out);
}